// Round 2
// baseline (633.743 us; speedup 1.0000x reference)
//
#include <hip/hip_runtime.h>
#include <hip/hip_bf16.h>

typedef unsigned short u16;
typedef __attribute__((ext_vector_type(8))) short short8;
typedef __attribute__((ext_vector_type(4))) float floatx4;

#define NPIX 12544   // 112*112 = 98 * 128
#define KDIM 768     // channels = 24 * 32
#define EPSF 1e-8f

// ---------------------------------------------------------------- async G->LDS
__device__ __forceinline__ void gload_lds16(const void* g, void* l) {
  __builtin_amdgcn_global_load_lds(
      (const __attribute__((address_space(1))) void*)g,
      (__attribute__((address_space(3))) void*)l, 16, 0, 0);
}

// ---------------------------------------------------------------- K1: column sum-of-squares partials
// grid (49, 8), block 256. pa/pb: [8][NPIX]
__global__ void colsumsq_kernel(const float* __restrict__ a, const float* __restrict__ b,
                                float* __restrict__ pa, float* __restrict__ pb) {
  int i = blockIdx.x * 256 + threadIdx.x;
  int c0 = blockIdx.y * 96;
  float sa = 0.f, sb = 0.f;
#pragma unroll 4
  for (int c = c0; c < c0 + 96; ++c) {
    float va = a[(size_t)c * NPIX + i];
    float vb = b[(size_t)c * NPIX + i];
    sa += va * va;
    sb += vb * vb;
  }
  pa[(size_t)blockIdx.y * NPIX + i] = sa;
  pb[(size_t)blockIdx.y * NPIX + i] = sb;
}

// ---------------------------------------------------------------- K2: 1/(sqrt(sum+eps)+eps)
// grid 49, block 256
__global__ void rnorm_kernel(const float* __restrict__ pa, const float* __restrict__ pb,
                             float* __restrict__ ra, float* __restrict__ rb) {
  int i = blockIdx.x * 256 + threadIdx.x;
  float sa = 0.f, sb = 0.f;
#pragma unroll
  for (int c = 0; c < 8; ++c) {
    sa += pa[(size_t)c * NPIX + i];
    sb += pb[(size_t)c * NPIX + i];
  }
  ra[i] = 1.f / (sqrtf(sa + EPSF) + EPSF);
  rb[i] = 1.f / (sqrtf(sb + EPSF) + EPSF);
}

// ---------------------------------------------------------------- K3: transpose + normalize + bf16 cast
// (C,N) f32 -> (N,C) bf16.  grid (392, 24, 2), block 256 (=32x8)
__global__ void transpose_kernel(const float* __restrict__ a, const float* __restrict__ b,
                                 const float* __restrict__ ra, const float* __restrict__ rb,
                                 u16* __restrict__ Ar, u16* __restrict__ Br) {
  const float* src = blockIdx.z ? b : a;
  const float* rn  = blockIdx.z ? rb : ra;
  u16* dst         = blockIdx.z ? Br : Ar;
  __shared__ float tile[32][33];
  int i0 = blockIdx.x * 32;
  int c0 = blockIdx.y * 32;
  int tx = threadIdx.x & 31;
  int ty = threadIdx.x >> 5;  // 0..7
#pragma unroll
  for (int d = 0; d < 4; ++d) {
    int c = c0 + ty + d * 8;
    tile[ty + d * 8][tx] = src[(size_t)c * NPIX + i0 + tx];
  }
  __syncthreads();
#pragma unroll
  for (int d = 0; d < 4; ++d) {
    int il = ty + d * 8;
    int gi = i0 + il;
    float v = tile[tx][il] * rn[gi];
    __hip_bfloat16 h = __float2bfloat16(v);
    dst[(size_t)gi * KDIM + c0 + tx] = *reinterpret_cast<u16*>(&h);
  }
}

// ---------------------------------------------------------------- K4: fused GEMM + row-max
// S[i][j] = sum_k Ar[i][k]*Br[j][k]; track max_j per row i.
// grid (8 chunks, 98 row tiles), block 256 (4 waves, 2x2; each wave = 64x64 via 4x4 MFMA 16x16x32)
__global__ __launch_bounds__(256) void gemm_max_kernel(const u16* __restrict__ Ar,
                                                       const u16* __restrict__ Br,
                                                       float* __restrict__ part_max) {
  __shared__ alignas(16) u16 As[128 * 32];
  __shared__ alignas(16) u16 Bs[128 * 32];
  __shared__ float s_max[2 * 128];

  const int tid = threadIdx.x;
  const int chunk = blockIdx.x;
  const int rt = blockIdx.y;
  const int wave = tid >> 6;
  const int lane = tid & 63;
  const int wx = wave & 1;
  const int wy = wave >> 1;
  const int l15 = lane & 15;
  const int quad = lane >> 4;

  s_max[tid] = -1e30f;  // 256 entries, covered exactly

  const int row_base = rt * 128;
  const int r0 = tid >> 2;        // 0..63
  const int kc = (tid & 3) * 8;   // 0,8,16,24

  const u16* pA0 = Ar + (size_t)(row_base + r0) * KDIM + kc;
  const u16* pA1 = Ar + (size_t)(row_base + r0 + 64) * KDIM + kc;
  u16* lA0 = &As[tid * 8];
  u16* lA1 = &As[2048 + tid * 8];
  u16* lB0 = &Bs[tid * 8];
  u16* lB1 = &Bs[2048 + tid * 8];

  for (int jt = chunk; jt < 98; jt += 8) {
    const int col_base = jt * 128;
    const u16* pB0 = Br + (size_t)(col_base + r0) * KDIM + kc;
    const u16* pB1 = Br + (size_t)(col_base + r0 + 64) * KDIM + kc;

    floatx4 acc[4][4];
#pragma unroll
    for (int mf = 0; mf < 4; ++mf)
#pragma unroll
      for (int nf = 0; nf < 4; ++nf) acc[mf][nf] = (floatx4){0.f, 0.f, 0.f, 0.f};

    for (int k0 = 0; k0 < KDIM; k0 += 32) {
      __syncthreads();  // previous tile's LDS reads done
      gload_lds16(pA0 + k0, lA0);
      gload_lds16(pA1 + k0, lA1);
      gload_lds16(pB0 + k0, lB0);
      gload_lds16(pB1 + k0, lB1);
      __syncthreads();  // staging drained (vmcnt(0) before barrier)

      short8 af[4], bf[4];
#pragma unroll
      for (int mf = 0; mf < 4; ++mf)
        af[mf] = *(const short8*)&As[(wy * 64 + mf * 16 + l15) * 32 + quad * 8];
#pragma unroll
      for (int nf = 0; nf < 4; ++nf)
        bf[nf] = *(const short8*)&Bs[(wx * 64 + nf * 16 + l15) * 32 + quad * 8];
#pragma unroll
      for (int mf = 0; mf < 4; ++mf)
#pragma unroll
        for (int nf = 0; nf < 4; ++nf)
          acc[mf][nf] = __builtin_amdgcn_mfma_f32_16x16x32_bf16(af[mf], bf[nf], acc[mf][nf], 0, 0, 0);
    }

    // epilogue: per-row max over this 128-col tile
    // C layout: col = l15 (+nf*16), row = quad*4 + r (+mf*16)
#pragma unroll
    for (int mf = 0; mf < 4; ++mf) {
#pragma unroll
      for (int r = 0; r < 4; ++r) {
        float best = acc[mf][0][r];
        best = fmaxf(best, acc[mf][1][r]);
        best = fmaxf(best, acc[mf][2][r]);
        best = fmaxf(best, acc[mf][3][r]);
        best = fmaxf(best, __shfl_xor(best, 1));
        best = fmaxf(best, __shfl_xor(best, 2));
        best = fmaxf(best, __shfl_xor(best, 4));
        best = fmaxf(best, __shfl_xor(best, 8));
        if (l15 == 0) {
          int row = wy * 64 + mf * 16 + quad * 4 + r;
          s_max[wx * 128 + row] = fmaxf(s_max[wx * 128 + row], best);
        }
      }
    }
    (void)col_base;
  }
  __syncthreads();
  if (tid < 128) {
    float m = fmaxf(s_max[tid], s_max[128 + tid]);
    part_max[(size_t)chunk * NPIX + row_base + tid] = m;
  }
}

// ---------------------------------------------------------------- K5: merge chunks + loss
// single block, 1024 threads; OUTPUT IS FLOAT32 (reference returns jnp.float32)
__global__ void finish_kernel(const float* __restrict__ pm, float* __restrict__ out) {
  float v = 0.f;
  for (int i = threadIdx.x; i < NPIX; i += 1024) {
    float m = pm[i];
#pragma unroll
    for (int c = 1; c < 8; ++c) m = fmaxf(m, pm[(size_t)c * NPIX + i]);
    v += 1.0f - m;
  }
#pragma unroll
  for (int off = 32; off > 0; off >>= 1) v += __shfl_down(v, off);
  __shared__ float red[16];
  int w = threadIdx.x >> 6;
  if ((threadIdx.x & 63) == 0) red[w] = v;
  __syncthreads();
  if (threadIdx.x == 0) {
    float s = 0.f;
#pragma unroll
    for (int k = 0; k < 16; ++k) s += red[k];
    out[0] = s * (1.0f / (float)NPIX);
  }
}

// ---------------------------------------------------------------- launcher
extern "C" void kernel_launch(void* const* d_in, const int* in_sizes, int n_in,
                              void* d_out, int out_size, void* d_ws, size_t ws_size,
                              hipStream_t stream) {
  const float* x = (const float*)d_in[0];
  const float* s = (const float*)d_in[1];
  char* ws = (char*)d_ws;
  // layout (bytes):
  float* pa       = (float*)(ws + 0);         //   401408
  float* pb       = (float*)(ws + 401408);    //   401408
  float* ra       = (float*)(ws + 802816);    //    50176
  float* rb       = (float*)(ws + 852992);    //    50176
  float* part_max = (float*)(ws + 903168);    //   401408
  u16*   Ar       = (u16*)(ws + 1304576);     // 19267584
  u16*   Br       = (u16*)(ws + 20572160);    // 19267584  -> total 39839744 B

  colsumsq_kernel<<<dim3(49, 8), 256, 0, stream>>>(x, s, pa, pb);
  rnorm_kernel<<<49, 256, 0, stream>>>(pa, pb, ra, rb);
  transpose_kernel<<<dim3(392, 24, 2), 256, 0, stream>>>(x, s, ra, rb, Ar, Br);
  gemm_max_kernel<<<dim3(8, 98), 256, 0, stream>>>(Ar, Br, part_max);
  finish_kernel<<<1, 1024, 0, stream>>>(part_max, (float*)d_out);
}

// Round 3
// 441.475 us; speedup vs baseline: 1.4355x; 1.4355x over previous
//
#include <hip/hip_runtime.h>
#include <hip/hip_bf16.h>

typedef unsigned short u16;
typedef unsigned int u32;
typedef __attribute__((ext_vector_type(8))) short short8;
typedef __attribute__((ext_vector_type(4))) float floatx4;

#define NPIX 12544   // 112*112 = 98 * 128
#define KDIM 768     // channels = 24 * 32
#define EPSF 1e-8f

// ---------------------------------------------------------------- async G->LDS
__device__ __forceinline__ void gload_lds16(const void* g, void* l) {
  __builtin_amdgcn_global_load_lds(
      (const __attribute__((address_space(1))) void*)g,
      (__attribute__((address_space(3))) void*)l, 16, 0, 0);
}

// sortable-uint encoding of float (monotone): max over enc == max over float
__device__ __forceinline__ u32 enc_f32(float f) {
  u32 u = __float_as_uint(f);
  return (u & 0x80000000u) ? ~u : (u | 0x80000000u);
}
__device__ __forceinline__ float dec_f32(u32 e) {
  u32 u = (e & 0x80000000u) ? (e & 0x7FFFFFFFu) : ~e;
  return __uint_as_float(u);
}

// ---------------------------------------------------------------- K1: column sum-of-squares partials
// grid (49, 8), block 256. pa/pb: [8][NPIX]
__global__ void colsumsq_kernel(const float* __restrict__ a, const float* __restrict__ b,
                                float* __restrict__ pa, float* __restrict__ pb) {
  int i = blockIdx.x * 256 + threadIdx.x;
  int c0 = blockIdx.y * 96;
  float sa = 0.f, sb = 0.f;
#pragma unroll 4
  for (int c = c0; c < c0 + 96; ++c) {
    float va = a[(size_t)c * NPIX + i];
    float vb = b[(size_t)c * NPIX + i];
    sa += va * va;
    sb += vb * vb;
  }
  pa[(size_t)blockIdx.y * NPIX + i] = sa;
  pb[(size_t)blockIdx.y * NPIX + i] = sb;
}

// ---------------------------------------------------------------- K2: 1/(sqrt(sum+eps)+eps) + zero the atomic-max buffer
// grid 49, block 256
__global__ void rnorm_kernel(const float* __restrict__ pa, const float* __restrict__ pb,
                             float* __restrict__ ra, float* __restrict__ rb,
                             u32* __restrict__ part) {
  int i = blockIdx.x * 256 + threadIdx.x;
  float sa = 0.f, sb = 0.f;
#pragma unroll
  for (int c = 0; c < 8; ++c) {
    sa += pa[(size_t)c * NPIX + i];
    sb += pb[(size_t)c * NPIX + i];
  }
  ra[i] = 1.f / (sqrtf(sa + EPSF) + EPSF);
  rb[i] = 1.f / (sqrtf(sb + EPSF) + EPSF);
  part[i] = 0u;  // encoded floor (< enc of any finite float)
}

// ---------------------------------------------------------------- K3: transpose + normalize + bf16 cast
// (C,N) f32 -> (N,C) bf16.  grid (392, 24, 2), block 256 (=32x8)
__global__ void transpose_kernel(const float* __restrict__ a, const float* __restrict__ b,
                                 const float* __restrict__ ra, const float* __restrict__ rb,
                                 u16* __restrict__ Ar, u16* __restrict__ Br) {
  const float* src = blockIdx.z ? b : a;
  const float* rn  = blockIdx.z ? rb : ra;
  u16* dst         = blockIdx.z ? Br : Ar;
  __shared__ float tile[32][33];
  int i0 = blockIdx.x * 32;
  int c0 = blockIdx.y * 32;
  int tx = threadIdx.x & 31;
  int ty = threadIdx.x >> 5;  // 0..7
#pragma unroll
  for (int d = 0; d < 4; ++d) {
    int c = c0 + ty + d * 8;
    tile[ty + d * 8][tx] = src[(size_t)c * NPIX + i0 + tx];
  }
  __syncthreads();
#pragma unroll
  for (int d = 0; d < 4; ++d) {
    int il = ty + d * 8;
    int gi = i0 + il;
    float v = tile[tx][il] * rn[gi];
    __hip_bfloat16 h = __float2bfloat16(v);
    dst[(size_t)gi * KDIM + c0 + tx] = *reinterpret_cast<u16*>(&h);
  }
}

// ---------------------------------------------------------------- K4: one 128x128 tile per block + row-max atomic
// grid (8, 13, 98): x = XCD chunk (13 contiguous col tiles for x<2, 12 for x>=2),
// y = col tile within chunk, z = row tile. linear%8 == x -> per-XCD B panel
// (~2.5 MB) pinned in that XCD's L2; A tiles stream with temporal locality.
__global__ __launch_bounds__(256) void gemm_max_kernel(const u16* __restrict__ Ar,
                                                       const u16* __restrict__ Br,
                                                       u32* __restrict__ part) {
  const int X = blockIdx.x;                 // XCD chunk
  const int t13 = blockIdx.y;
  const int live = (X < 2) ? 13 : 12;
  if (t13 >= live) return;                  // dead padding block
  const int ct = (X < 2) ? (X * 13 + t13) : (X * 12 + 2 + t13);
  const int rt = blockIdx.z;

  __shared__ alignas(16) u16 As[128 * 32];
  __shared__ alignas(16) u16 Bs[128 * 32];
  __shared__ float s_max[2 * 128];

  const int tid = threadIdx.x;
  const int wave = tid >> 6;
  const int lane = tid & 63;
  const int wx = wave & 1;
  const int wy = wave >> 1;
  const int l15 = lane & 15;
  const int quad = lane >> 4;

  const int row_base = rt * 128;
  const int col_base = ct * 128;

  // staging: lane/thread -> LDS slot tid (16B units); swizzled k-quad so that
  // ds_read_b128 at row-stride 64B is bank-conflict-free.
  // layout: chunk for (row r, kquad q) lives at slot r*4 + ((q + (r>>1)) & 3)
  const int r0 = tid >> 2;                              // 0..63
  const int qs = ((tid & 3) - (tid >> 3)) & 3;          // inverse swizzle
  const int kc = qs * 8;

  const u16* pA0 = Ar + (size_t)(row_base + r0) * KDIM + kc;
  const u16* pA1 = Ar + (size_t)(row_base + r0 + 64) * KDIM + kc;
  const u16* pB0 = Br + (size_t)(col_base + r0) * KDIM + kc;
  const u16* pB1 = Br + (size_t)(col_base + r0 + 64) * KDIM + kc;
  u16* lA0 = &As[tid * 8];
  u16* lA1 = &As[2048 + tid * 8];
  u16* lB0 = &Bs[tid * 8];
  u16* lB1 = &Bs[2048 + tid * 8];

  floatx4 acc[4][4];
#pragma unroll
  for (int mf = 0; mf < 4; ++mf)
#pragma unroll
    for (int nf = 0; nf < 4; ++nf) acc[mf][nf] = (floatx4){0.f, 0.f, 0.f, 0.f};

  // ds_read addresses are k-invariant: precompute swizzled offsets
  // row Ra, kquad quad -> As[Ra*32 + ((quad + (Ra>>1))&3)*8]
  for (int k0 = 0; k0 < KDIM; k0 += 32) {
    __syncthreads();  // previous step's LDS reads done
    gload_lds16(pA0 + k0, lA0);
    gload_lds16(pA1 + k0, lA1);
    gload_lds16(pB0 + k0, lB0);
    gload_lds16(pB1 + k0, lB1);
    __syncthreads();  // staging drained

    short8 af[4], bf[4];
#pragma unroll
    for (int mf = 0; mf < 4; ++mf) {
      const int Ra = wy * 64 + mf * 16 + l15;
      af[mf] = *(const short8*)&As[Ra * 32 + (((quad + (Ra >> 1)) & 3) * 8)];
    }
#pragma unroll
    for (int nf = 0; nf < 4; ++nf) {
      const int Rb = wx * 64 + nf * 16 + l15;
      bf[nf] = *(const short8*)&Bs[Rb * 32 + (((quad + (Rb >> 1)) & 3) * 8)];
    }
#pragma unroll
    for (int mf = 0; mf < 4; ++mf)
#pragma unroll
      for (int nf = 0; nf < 4; ++nf)
        acc[mf][nf] = __builtin_amdgcn_mfma_f32_16x16x32_bf16(af[mf], bf[nf], acc[mf][nf], 0, 0, 0);
  }

  // epilogue: per-row max over the 128-col tile.
  // C layout: col = l15 (+nf*16), row = quad*4 + r (+mf*16)
#pragma unroll
  for (int mf = 0; mf < 4; ++mf) {
#pragma unroll
    for (int r = 0; r < 4; ++r) {
      float best = acc[mf][0][r];
      best = fmaxf(best, acc[mf][1][r]);
      best = fmaxf(best, acc[mf][2][r]);
      best = fmaxf(best, acc[mf][3][r]);
      best = fmaxf(best, __shfl_xor(best, 1));
      best = fmaxf(best, __shfl_xor(best, 2));
      best = fmaxf(best, __shfl_xor(best, 4));
      best = fmaxf(best, __shfl_xor(best, 8));
      if (l15 == 0) {
        int row = wy * 64 + mf * 16 + quad * 4 + r;
        s_max[wx * 128 + row] = best;   // each entry written exactly once
      }
    }
  }
  __syncthreads();
  if (tid < 128) {
    float m = fmaxf(s_max[tid], s_max[128 + tid]);
    atomicMax(&part[row_base + tid], enc_f32(m));
  }
}

// ---------------------------------------------------------------- K5: decode + loss
// single block, 1024 threads; output fp32 scalar
__global__ void finish_kernel(const u32* __restrict__ part, float* __restrict__ out) {
  float v = 0.f;
  for (int i = threadIdx.x; i < NPIX; i += 1024) {
    v += 1.0f - dec_f32(part[i]);
  }
#pragma unroll
  for (int off = 32; off > 0; off >>= 1) v += __shfl_down(v, off);
  __shared__ float red[16];
  int w = threadIdx.x >> 6;
  if ((threadIdx.x & 63) == 0) red[w] = v;
  __syncthreads();
  if (threadIdx.x == 0) {
    float s = 0.f;
#pragma unroll
    for (int k = 0; k < 16; ++k) s += red[k];
    out[0] = s * (1.0f / (float)NPIX);
  }
}

// ---------------------------------------------------------------- launcher
extern "C" void kernel_launch(void* const* d_in, const int* in_sizes, int n_in,
                              void* d_out, int out_size, void* d_ws, size_t ws_size,
                              hipStream_t stream) {
  const float* x = (const float*)d_in[0];
  const float* s = (const float*)d_in[1];
  char* ws = (char*)d_ws;
  // layout (bytes):
  float* pa   = (float*)(ws + 0);         //   401408
  float* pb   = (float*)(ws + 401408);    //   401408
  float* ra   = (float*)(ws + 802816);    //    50176
  float* rb   = (float*)(ws + 852992);    //    50176
  u32*   part = (u32*)  (ws + 903168);    //    50176 (encoded row maxima)
  u16*   Ar   = (u16*)  (ws + 953344);    // 19267584
  u16*   Br   = (u16*)  (ws + 20220928);  // 19267584  -> total 39488512 B

  colsumsq_kernel<<<dim3(49, 8), 256, 0, stream>>>(x, s, pa, pb);
  rnorm_kernel<<<49, 256, 0, stream>>>(pa, pb, ra, rb, part);
  transpose_kernel<<<dim3(392, 24, 2), 256, 0, stream>>>(x, s, ra, rb, Ar, Br);
  gemm_max_kernel<<<dim3(8, 13, 98), 256, 0, stream>>>(Ar, Br, part);
  finish_kernel<<<1, 1024, 0, stream>>>(part, (float*)d_out);
}